// Round 7
// baseline (123.434 us; speedup 1.0000x reference)
//
#include <hip/hip_runtime.h>
#include <hip/hip_bf16.h>

typedef short short8 __attribute__((ext_vector_type(8)));
typedef float f32x4 __attribute__((ext_vector_type(4)));
typedef float f32x2 __attribute__((ext_vector_type(2)));

__device__ __forceinline__ float bf2f(unsigned short v) {
    unsigned int u = ((unsigned int)v) << 16;
    float f;
    __builtin_memcpy(&f, &u, 4);
    return f;
}

__device__ __forceinline__ unsigned short f2bf(float f) {
    unsigned int u;
    __builtin_memcpy(&u, &f, 4);
    u += 0x7fffu + ((u >> 16) & 1u);   // RNE
    return (unsigned short)(u >> 16);
}

__device__ __forceinline__ unsigned int pack2(float a, float b) {
    return (unsigned int)f2bf(a) | ((unsigned int)f2bf(b) << 16);
}

// truncation pack (1 v_perm_b32): a -> low16, b -> high16
__device__ __forceinline__ unsigned int pack_trunc(float a, float b) {
    unsigned int ua, ub;
    __builtin_memcpy(&ua, &a, 4);
    __builtin_memcpy(&ub, &b, 4);
    return __builtin_amdgcn_perm(ub, ua, 0x07060302u);
}

// split a,b into bf16 hi + bf16 lo packed pairs (hi+lo ~ fp32-accurate)
__device__ __forceinline__ void split2(float a, float b,
                                       unsigned int& hi, unsigned int& lo) {
    unsigned short ah = f2bf(a), bh = f2bf(b);
    float al = a - bf2f(ah), bl = b - bf2f(bh);
    hi = (unsigned int)ah | ((unsigned int)bh << 16);
    lo = (unsigned int)f2bf(al) | ((unsigned int)f2bf(bl) << 16);
}

// Runtime dtype dispatch (proven fp32 on this harness, kept for robustness).
__device__ __forceinline__ float loadv(const void* p, int idx, bool is_fp32) {
    return is_fp32 ? ((const float*)p)[idx] : bf2f(((const unsigned short*)p)[idx]);
}
__device__ __forceinline__ bool detect_fp32(const void* x, int tid, int* flag_sh) {
    if (tid < 64) {                      // exactly wave 0
        unsigned int w = ((const unsigned int*)x)[tid];
        unsigned int e = (w >> 7) & 0xFFu;   // exponent of low u16 as bf16
        unsigned long long m = __ballot(e > 140u);
        if (tid == 0) *flag_sh = (__popcll(m) >= 8) ? 1 : 0;
    }
    __syncthreads();
    return *flag_sh != 0;
}

// ---------------------------------------------------------------------------
// Kernel 1: projections (split-bf16 MFMA GEMM), 256 WGs x 512 thr (8 waves,
// 2 waves/SIMD). Each WG owns 32 voxel rows; wave w loads its 16-row
// A-fragment once (rt = w>>2) and computes 1-2 of the 6 (matrix, col-half)
// tiles.  (best-measured configuration, rounds 3/6: 94.0 / 93.9 us)
// ---------------------------------------------------------------------------
__global__ __launch_bounds__(512) void proj_kernel(
    const void* __restrict__ x,
    const void* __restrict__ Wf, const void* __restrict__ bfv,
    const void* __restrict__ Wg, const void* __restrict__ bgv,
    const void* __restrict__ Wh, const void* __restrict__ bhv,
    unsigned short* __restrict__ F, unsigned short* __restrict__ G,
    unsigned short* __restrict__ Ht) {
    __shared__ unsigned int WTh[3 * 32 * 36];   // [m][n][p] packed hi pairs
    __shared__ unsigned int WTl[3 * 32 * 36];   // lo pairs
    __shared__ float bL[96];
    __shared__ int dflag;
    int tid = threadIdx.x;
    bool fp32 = detect_fp32(x, tid, &dflag);
    int lane = tid & 63, wave = tid >> 6;
    int Q = lane >> 4, l15 = lane & 15;

    const void* Ws[3] = {Wf, Wg, Wh};
    const void* bs[3] = {bfv, bgv, bhv};

    // ---- stage split W into LDS: 3072 kpairs over 512 threads ----
    for (int i = tid; i < 3072; i += 512) {
        int m = i >> 10;                 // matrix
        int r = i & 1023;
        int p = r >> 5, n = r & 31;      // kpair, col
        float e0 = loadv(Ws[m], (2 * p) * 32 + n, fp32);
        float e1 = loadv(Ws[m], (2 * p + 1) * 32 + n, fp32);
        unsigned int hi, lo;
        split2(e0, e1, hi, lo);
        WTh[(m * 32 + n) * 36 + p] = hi;
        WTl[(m * 32 + n) * 36 + p] = lo;
    }
    if (tid < 96) bL[tid] = loadv(bs[tid >> 5], tid & 31, fp32);

    // ---- A fragments: wave w>>2 selects 16-row half, loaded ONCE ----
    int rt = wave >> 2;
    int row0 = (blockIdx.x << 5) + (rt << 4);    // global voxel row (0..8191)
    short8 a0h, a0l, a1h, a1l;
    {
        int base = (row0 + l15) * 64 + Q * 8;
        union { unsigned int u[4]; short8 s8; } A0h, A0l, A1h, A1l;
        if (fp32) {
            const float* xf = (const float*)x;
            f32x4 v0 = *(const f32x4*)(xf + base);
            f32x4 v1 = *(const f32x4*)(xf + base + 4);
            f32x4 w0 = *(const f32x4*)(xf + base + 32);
            f32x4 w1 = *(const f32x4*)(xf + base + 36);
            split2(v0[0], v0[1], A0h.u[0], A0l.u[0]);
            split2(v0[2], v0[3], A0h.u[1], A0l.u[1]);
            split2(v1[0], v1[1], A0h.u[2], A0l.u[2]);
            split2(v1[2], v1[3], A0h.u[3], A0l.u[3]);
            split2(w0[0], w0[1], A1h.u[0], A1l.u[0]);
            split2(w0[2], w0[3], A1h.u[1], A1l.u[1]);
            split2(w1[0], w1[1], A1h.u[2], A1l.u[2]);
            split2(w1[2], w1[3], A1h.u[3], A1l.u[3]);
        } else {
            const unsigned short* xb = (const unsigned short*)x;
            A0h.s8 = *(const short8*)(xb + base);
            A1h.s8 = *(const short8*)(xb + base + 32);
            A0l.u[0] = A0l.u[1] = A0l.u[2] = A0l.u[3] = 0;
            A1l = A0l;
        }
        a0h = A0h.s8; a0l = A0l.s8; a1h = A1h.s8; a1l = A1l.s8;
    }
    __syncthreads();

    // ---- proj col-tile tasks: wave&3 -> (m,cb); waves with c4<2 also do Ht ----
    auto proj_tile = [&](int m, int cb) {
        int rowbase = (m * 32 + cb * 16 + l15) * 36;
        union { uint4 v; short8 s8; } B0h, B0l, B1h, B1l;
        B0h.v = *(const uint4*)&WTh[rowbase + Q * 4];
        B1h.v = *(const uint4*)&WTh[rowbase + 16 + Q * 4];
        B0l.v = *(const uint4*)&WTl[rowbase + Q * 4];
        B1l.v = *(const uint4*)&WTl[rowbase + 16 + Q * 4];
        f32x4 z = {0.f, 0.f, 0.f, 0.f};
        f32x4 acc = __builtin_amdgcn_mfma_f32_16x16x32_bf16(a0h, B0h.s8, z, 0, 0, 0);
        acc = __builtin_amdgcn_mfma_f32_16x16x32_bf16(a0h, B0l.s8, acc, 0, 0, 0);
        acc = __builtin_amdgcn_mfma_f32_16x16x32_bf16(a0l, B0h.s8, acc, 0, 0, 0);
        acc = __builtin_amdgcn_mfma_f32_16x16x32_bf16(a1h, B1h.s8, acc, 0, 0, 0);
        acc = __builtin_amdgcn_mfma_f32_16x16x32_bf16(a1h, B1l.s8, acc, 0, 0, 0);
        acc = __builtin_amdgcn_mfma_f32_16x16x32_bf16(a1l, B1h.s8, acc, 0, 0, 0);
        float bias = bL[m * 32 + cb * 16 + l15];
        if (m < 2) {
            unsigned short* dst = (m == 0) ? F : G;
#pragma unroll
            for (int r = 0; r < 4; r++)
                dst[(row0 + Q * 4 + r) * 32 + cb * 16 + l15] = f2bf(acc[r] + bias);
        } else {
            int bb = row0 >> 12;
            int n0 = (row0 & 4095) + Q * 4;
            uint2 pk;
            pk.x = pack2(acc[0] + bias, acc[1] + bias);
            pk.y = pack2(acc[2] + bias, acc[3] + bias);
            *(uint2*)(Ht + bb * 131072 + (cb * 16 + l15) * 4096 + n0) = pk;
        }
    };
    int c4 = wave & 3;
    proj_tile(c4 >> 1, c4 & 1);          // (m=0/1, cb)
    if (c4 < 2) proj_tile(2, c4);        // Ht tiles
}

// ---------------------------------------------------------------------------
// Kernel 2: flash attention (no-max exp) + fused output projection.
// (identical to the best-measured round-3/6 version; see comments there)
// DIAGNOSTIC THIS ROUND: launched 3x (idempotent — reads x/F/G/Ht/weights,
// deterministically writes out).  Delta dur = 2*(attn + launch gap),
// discriminating "attn ~5-8us, harness-fixed floor dominates" from
// "attn ~40us latency-bound" — three blind rewrites (R4/R5) moved total
// by only +-5us, so the next edit must be measurement, not a guess.
// ---------------------------------------------------------------------------
__global__ __launch_bounds__(1024) void attn_kernel(
    const unsigned short* __restrict__ F, const unsigned short* __restrict__ G,
    const unsigned short* __restrict__ Ht,
    const void* __restrict__ x,
    const void* __restrict__ Wo, const void* __restrict__ bo,
    const void* __restrict__ gamma_p,
    void* __restrict__ out) {
    __shared__ __attribute__((aligned(16))) unsigned short P_sh[16][2][16][40];
    __shared__ float O_lds[16][32][32];
    __shared__ float l_lds[16][32];
    __shared__ float Om[32][33];
    __shared__ float lmg[32];
    __shared__ float WoL[32][64];
    __shared__ float boL[64];
    __shared__ int dflag;

    int tid = threadIdx.x;
    bool fp32 = detect_fp32(x, tid, &dflag);

    for (int i = tid; i < 2048; i += 1024) WoL[i >> 6][i & 63] = loadv(Wo, i, fp32);
    if (tid < 64) boL[tid] = loadv(bo, tid, fp32);

    int bx = blockIdx.x;            // 0..255
    int b = bx >> 7;                // batch
    int q0 = (bx & 127) << 5;       // 32 queries per WG
    int wave = tid >> 6;            // k-split index 0..15
    int lane = tid & 63;
    int Q = lane >> 4, l15 = lane & 15;

    const unsigned short* Fb = F + (b << 17);
    const unsigned short* Gb = G + (b << 17);
    const unsigned short* Htb = Ht + (b << 17);

    // B operands of S^T: queries as N.  g0 = q-tile [q0,q0+16), g1 = +16.
    short8 g0 = *(const short8*)(Gb + ((q0 + l15) << 5) + (Q << 3));
    short8 g1 = *(const short8*)(Gb + ((q0 + 16 + l15) << 5) + (Q << 3));

    f32x4 O00 = {0.f, 0.f, 0.f, 0.f}, O01 = O00, O10 = O00, O11 = O00;
    float ls0 = 0.f, ls1 = 0.f;

    int k_begin = wave << 8;        // 256 keys per wave
    // prime prefetch registers with iteration 0
    short8 af0 = *(const short8*)(Fb + ((k_begin + l15) << 5) + (Q << 3));
    short8 af1 = *(const short8*)(Fb + ((k_begin + 16 + l15) << 5) + (Q << 3));
    short8 bh0 = *(const short8*)(Htb + (l15 << 12) + k_begin + (Q << 3));
    short8 bh1 = *(const short8*)(Htb + ((16 + l15) << 12) + k_begin + (Q << 3));

    for (int it = 0; it < 8; ++it) {
        // issue next iteration's loads first (clamped; redundant at it=7)
        int itn = (it < 7) ? it + 1 : 7;
        int kn = k_begin + (itn << 5);
        short8 naf0 = *(const short8*)(Fb + ((kn + l15) << 5) + (Q << 3));
        short8 naf1 = *(const short8*)(Fb + ((kn + 16 + l15) << 5) + (Q << 3));
        short8 nbh0 = *(const short8*)(Htb + (l15 << 12) + kn + (Q << 3));
        short8 nbh1 = *(const short8*)(Htb + ((16 + l15) << 12) + kn + (Q << 3));

        f32x4 z = {0.f, 0.f, 0.f, 0.f};
        f32x4 c00 = __builtin_amdgcn_mfma_f32_16x16x32_bf16(af0, g0, z, 0, 0, 0);
        f32x4 c01 = __builtin_amdgcn_mfma_f32_16x16x32_bf16(af1, g0, z, 0, 0, 0);
        f32x4 c10 = __builtin_amdgcn_mfma_f32_16x16x32_bf16(af0, g1, z, 0, 0, 0);
        f32x4 c11 = __builtin_amdgcn_mfma_f32_16x16x32_bf16(af1, g1, z, 0, 0, 0);
        // c[r] = S[q][key = kk + half*16 + Q*4 + r], q = q-tile base + l15

        float e00[4], e01[4], e10[4], e11[4];
#pragma unroll
        for (int r = 0; r < 4; r++) {
            e00[r] = __expf(c00[r]); e01[r] = __expf(c01[r]);
            e10[r] = __expf(c10[r]); e11[r] = __expf(c11[r]);
            ls0 += e00[r] + e01[r];
            ls1 += e10[r] + e11[r];
        }

        // P (C-layout) -> LDS rows [query][key], bf16 by truncation
        uint2 w0, w1;
        w0.x = pack_trunc(e00[0], e00[1]); w0.y = pack_trunc(e00[2], e00[3]);
        w1.x = pack_trunc(e01[0], e01[1]); w1.y = pack_trunc(e01[2], e01[3]);
        *(uint2*)&P_sh[wave][0][l15][Q * 4] = w0;
        *(uint2*)&P_sh[wave][0][l15][16 + Q * 4] = w1;
        uint2 w2, w3;
        w2.x = pack_trunc(e10[0], e10[1]); w2.y = pack_trunc(e10[2], e10[3]);
        w3.x = pack_trunc(e11[0], e11[1]); w3.y = pack_trunc(e11[2], e11[3]);
        *(uint2*)&P_sh[wave][1][l15][Q * 4] = w2;
        *(uint2*)&P_sh[wave][1][l15][16 + Q * 4] = w3;

        // read back in A-layout: A[q=l15][k=Q*8+j]
        short8 pf0 = *(const short8*)&P_sh[wave][0][l15][Q * 8];
        short8 pf1 = *(const short8*)&P_sh[wave][1][l15][Q * 8];

        O00 = __builtin_amdgcn_mfma_f32_16x16x32_bf16(pf0, bh0, O00, 0, 0, 0);
        O01 = __builtin_amdgcn_mfma_f32_16x16x32_bf16(pf0, bh1, O01, 0, 0, 0);
        O10 = __builtin_amdgcn_mfma_f32_16x16x32_bf16(pf1, bh0, O10, 0, 0, 0);
        O11 = __builtin_amdgcn_mfma_f32_16x16x32_bf16(pf1, bh1, O11, 0, 0, 0);

        af0 = naf0; af1 = naf1; bh0 = nbh0; bh1 = nbh1;
    }

    // per-wave l reduction across quads (each quad held distinct keys)
    ls0 += __shfl_xor(ls0, 16); ls0 += __shfl_xor(ls0, 32);
    ls1 += __shfl_xor(ls1, 16); ls1 += __shfl_xor(ls1, 32);
    if (Q == 0) {
        l_lds[wave][l15] = ls0;
        l_lds[wave][16 + l15] = ls1;
    }
    // O partials: D[row=q-in-tile=Q*4+r][col=cbar=l15]
#pragma unroll
    for (int r = 0; r < 4; r++) {
        O_lds[wave][(Q << 2) | r][l15]             = O00[r];
        O_lds[wave][(Q << 2) | r][16 + l15]        = O01[r];
        O_lds[wave][16 + ((Q << 2) | r)][l15]      = O10[r];
        O_lds[wave][16 + ((Q << 2) | r)][16 + l15] = O11[r];
    }
    __syncthreads();

    // merge k-split partials (plain sums)
    if (tid < 32) {
        float s = 0.f;
#pragma unroll
        for (int w = 0; w < 16; w++) s += l_lds[w][tid];
        lmg[tid] = 1.0f / s;
    }
    {
        int q = tid >> 5, c = tid & 31;   // 1024 threads = 1024 elements
        float s = 0.f;
#pragma unroll
        for (int w = 0; w < 16; w++) s += O_lds[w][q][c];
        Om[q][c] = s;
    }
    __syncthreads();

    // output projection + residual: thread -> (q = tid>>5, 2 channels)
    int q = tid >> 5;
    int ch = (tid & 31) << 1;
    float a0 = 0.f, a1 = 0.f;
#pragma unroll
    for (int c = 0; c < 32; c++) {
        float ob = Om[q][c];
        f32x2 wr = *(const f32x2*)&WoL[c][ch];
        a0 += ob * wr[0]; a1 += ob * wr[1];
    }
    float inv = lmg[q];
    float gam = loadv(gamma_p, 0, fp32);
    int gq = q0 + q;
    int obase = (((b << 12) + gq) << 6) + ch;
    if (fp32) {
        f32x2 xv = *(const f32x2*)((const float*)x + obase);
        f32x2 ov;
        ov[0] = xv[0] + gam * (a0 * inv + boL[ch + 0]);
        ov[1] = xv[1] + gam * (a1 * inv + boL[ch + 1]);
        *(f32x2*)((float*)out + obase) = ov;
    } else {
        const unsigned short* xb = (const unsigned short*)x;
        unsigned short* ob16 = (unsigned short*)out;
        unsigned int pk = pack2(bf2f(xb[obase + 0]) + gam * (a0 * inv + boL[ch + 0]),
                                bf2f(xb[obase + 1]) + gam * (a1 * inv + boL[ch + 1]));
        *(unsigned int*)(ob16 + obase) = pk;
    }
}

extern "C" void kernel_launch(void* const* d_in, const int* in_sizes, int n_in,
                              void* d_out, int out_size, void* d_ws, size_t ws_size,
                              hipStream_t stream) {
    const void* x   = d_in[0];
    const void* Wf  = d_in[1];
    const void* bfv = d_in[2];
    const void* Wg  = d_in[3];
    const void* bgv = d_in[4];
    const void* Wh  = d_in[5];
    const void* bhv = d_in[6];
    const void* Wo  = d_in[7];
    const void* bo  = d_in[8];
    const void* gam = d_in[9];

    unsigned short* F  = (unsigned short*)d_ws;       // [B][N][32] bf16
    unsigned short* G  = F + 262144;                  // [B][N][32] bf16
    unsigned short* Ht = G + 262144;                  // [B][32][N] bf16

    proj_kernel<<<256, 512, 0, stream>>>(x, Wf, bfv, Wg, bgv, Wh, bhv, F, G, Ht);
    // DIAGNOSTIC: attn launched 3x (idempotent). Delta vs round 6's 93.9 us
    // = 2*(attn_dur + launch_gap). See decision rule in round notes.
    attn_kernel<<<256, 1024, 0, stream>>>(F, G, Ht, x, Wo, bo, gam, d_out);
    attn_kernel<<<256, 1024, 0, stream>>>(F, G, Ht, x, Wo, bo, gam, d_out);
    attn_kernel<<<256, 1024, 0, stream>>>(F, G, Ht, x, Wo, bo, gam, d_out);
}

// Round 8
// 92.551 us; speedup vs baseline: 1.3337x; 1.3337x over previous
//
#include <hip/hip_runtime.h>
#include <hip/hip_bf16.h>

typedef short short8 __attribute__((ext_vector_type(8)));
typedef float f32x4 __attribute__((ext_vector_type(4)));
typedef float f32x2 __attribute__((ext_vector_type(2)));

__device__ __forceinline__ float bf2f(unsigned short v) {
    unsigned int u = ((unsigned int)v) << 16;
    float f;
    __builtin_memcpy(&f, &u, 4);
    return f;
}

__device__ __forceinline__ unsigned short f2bf(float f) {
    unsigned int u;
    __builtin_memcpy(&u, &f, 4);
    u += 0x7fffu + ((u >> 16) & 1u);   // RNE
    return (unsigned short)(u >> 16);
}

__device__ __forceinline__ unsigned int pack2(float a, float b) {
    return (unsigned int)f2bf(a) | ((unsigned int)f2bf(b) << 16);
}

// truncation pack (1 v_perm_b32): a -> low16, b -> high16
__device__ __forceinline__ unsigned int pack_trunc(float a, float b) {
    unsigned int ua, ub;
    __builtin_memcpy(&ua, &a, 4);
    __builtin_memcpy(&ub, &b, 4);
    return __builtin_amdgcn_perm(ub, ua, 0x07060302u);
}

// split a,b into bf16 hi + bf16 lo packed pairs (hi+lo ~ fp32-accurate)
__device__ __forceinline__ void split2(float a, float b,
                                       unsigned int& hi, unsigned int& lo) {
    unsigned short ah = f2bf(a), bh = f2bf(b);
    float al = a - bf2f(ah), bl = b - bf2f(bh);
    hi = (unsigned int)ah | ((unsigned int)bh << 16);
    lo = (unsigned int)f2bf(al) | ((unsigned int)f2bf(bl) << 16);
}

// Runtime dtype dispatch (proven fp32 on this harness, kept for robustness).
__device__ __forceinline__ float loadv(const void* p, int idx, bool is_fp32) {
    return is_fp32 ? ((const float*)p)[idx] : bf2f(((const unsigned short*)p)[idx]);
}
__device__ __forceinline__ bool detect_fp32(const void* x, int tid, int* flag_sh) {
    if (tid < 64) {                      // exactly wave 0
        unsigned int w = ((const unsigned int*)x)[tid];
        unsigned int e = (w >> 7) & 0xFFu;   // exponent of low u16 as bf16
        unsigned long long m = __ballot(e > 140u);
        if (tid == 0) *flag_sh = (__popcll(m) >= 8) ? 1 : 0;
    }
    __syncthreads();
    return *flag_sh != 0;
}

// ---------------------------------------------------------------------------
// Kernel 1: projections (split-bf16 MFMA GEMM), 256 WGs x 512 thr (8 waves,
// 2 waves/SIMD). Each WG owns 32 voxel rows; wave w loads its 16-row
// A-fragment once (rt = w>>2) and computes 1-2 of the 6 (matrix, col-half)
// tiles.  (best-measured configuration, rounds 3/6: 94.0 / 93.9 us)
// ---------------------------------------------------------------------------
__global__ __launch_bounds__(512) void proj_kernel(
    const void* __restrict__ x,
    const void* __restrict__ Wf, const void* __restrict__ bfv,
    const void* __restrict__ Wg, const void* __restrict__ bgv,
    const void* __restrict__ Wh, const void* __restrict__ bhv,
    unsigned short* __restrict__ F, unsigned short* __restrict__ G,
    unsigned short* __restrict__ Ht) {
    __shared__ unsigned int WTh[3 * 32 * 36];   // [m][n][p] packed hi pairs
    __shared__ unsigned int WTl[3 * 32 * 36];   // lo pairs
    __shared__ float bL[96];
    __shared__ int dflag;
    int tid = threadIdx.x;
    bool fp32 = detect_fp32(x, tid, &dflag);
    int lane = tid & 63, wave = tid >> 6;
    int Q = lane >> 4, l15 = lane & 15;

    const void* Ws[3] = {Wf, Wg, Wh};
    const void* bs[3] = {bfv, bgv, bhv};

    // ---- stage split W into LDS: 3072 kpairs over 512 threads ----
    for (int i = tid; i < 3072; i += 512) {
        int m = i >> 10;                 // matrix
        int r = i & 1023;
        int p = r >> 5, n = r & 31;      // kpair, col
        float e0 = loadv(Ws[m], (2 * p) * 32 + n, fp32);
        float e1 = loadv(Ws[m], (2 * p + 1) * 32 + n, fp32);
        unsigned int hi, lo;
        split2(e0, e1, hi, lo);
        WTh[(m * 32 + n) * 36 + p] = hi;
        WTl[(m * 32 + n) * 36 + p] = lo;
    }
    if (tid < 96) bL[tid] = loadv(bs[tid >> 5], tid & 31, fp32);

    // ---- A fragments: wave w>>2 selects 16-row half, loaded ONCE ----
    int rt = wave >> 2;
    int row0 = (blockIdx.x << 5) + (rt << 4);    // global voxel row (0..8191)
    short8 a0h, a0l, a1h, a1l;
    {
        int base = (row0 + l15) * 64 + Q * 8;
        union { unsigned int u[4]; short8 s8; } A0h, A0l, A1h, A1l;
        if (fp32) {
            const float* xf = (const float*)x;
            f32x4 v0 = *(const f32x4*)(xf + base);
            f32x4 v1 = *(const f32x4*)(xf + base + 4);
            f32x4 w0 = *(const f32x4*)(xf + base + 32);
            f32x4 w1 = *(const f32x4*)(xf + base + 36);
            split2(v0[0], v0[1], A0h.u[0], A0l.u[0]);
            split2(v0[2], v0[3], A0h.u[1], A0l.u[1]);
            split2(v1[0], v1[1], A0h.u[2], A0l.u[2]);
            split2(v1[2], v1[3], A0h.u[3], A0l.u[3]);
            split2(w0[0], w0[1], A1h.u[0], A1l.u[0]);
            split2(w0[2], w0[3], A1h.u[1], A1l.u[1]);
            split2(w1[0], w1[1], A1h.u[2], A1l.u[2]);
            split2(w1[2], w1[3], A1h.u[3], A1l.u[3]);
        } else {
            const unsigned short* xb = (const unsigned short*)x;
            A0h.s8 = *(const short8*)(xb + base);
            A1h.s8 = *(const short8*)(xb + base + 32);
            A0l.u[0] = A0l.u[1] = A0l.u[2] = A0l.u[3] = 0;
            A1l = A0l;
        }
        a0h = A0h.s8; a0l = A0l.s8; a1h = A1h.s8; a1l = A1l.s8;
    }
    __syncthreads();

    // ---- proj col-tile tasks: wave&3 -> (m,cb); waves with c4<2 also do Ht ----
    auto proj_tile = [&](int m, int cb) {
        int rowbase = (m * 32 + cb * 16 + l15) * 36;
        union { uint4 v; short8 s8; } B0h, B0l, B1h, B1l;
        B0h.v = *(const uint4*)&WTh[rowbase + Q * 4];
        B1h.v = *(const uint4*)&WTh[rowbase + 16 + Q * 4];
        B0l.v = *(const uint4*)&WTl[rowbase + Q * 4];
        B1l.v = *(const uint4*)&WTl[rowbase + 16 + Q * 4];
        f32x4 z = {0.f, 0.f, 0.f, 0.f};
        f32x4 acc = __builtin_amdgcn_mfma_f32_16x16x32_bf16(a0h, B0h.s8, z, 0, 0, 0);
        acc = __builtin_amdgcn_mfma_f32_16x16x32_bf16(a0h, B0l.s8, acc, 0, 0, 0);
        acc = __builtin_amdgcn_mfma_f32_16x16x32_bf16(a0l, B0h.s8, acc, 0, 0, 0);
        acc = __builtin_amdgcn_mfma_f32_16x16x32_bf16(a1h, B1h.s8, acc, 0, 0, 0);
        acc = __builtin_amdgcn_mfma_f32_16x16x32_bf16(a1h, B1l.s8, acc, 0, 0, 0);
        acc = __builtin_amdgcn_mfma_f32_16x16x32_bf16(a1l, B1h.s8, acc, 0, 0, 0);
        float bias = bL[m * 32 + cb * 16 + l15];
        if (m < 2) {
            unsigned short* dst = (m == 0) ? F : G;
#pragma unroll
            for (int r = 0; r < 4; r++)
                dst[(row0 + Q * 4 + r) * 32 + cb * 16 + l15] = f2bf(acc[r] + bias);
        } else {
            int bb = row0 >> 12;
            int n0 = (row0 & 4095) + Q * 4;
            uint2 pk;
            pk.x = pack2(acc[0] + bias, acc[1] + bias);
            pk.y = pack2(acc[2] + bias, acc[3] + bias);
            *(uint2*)(Ht + bb * 131072 + (cb * 16 + l15) * 4096 + n0) = pk;
        }
    };
    int c4 = wave & 3;
    proj_tile(c4 >> 1, c4 & 1);          // (m=0/1, cb)
    if (c4 < 2) proj_tile(2, c4);        // Ht tiles
}

// ---------------------------------------------------------------------------
// Kernel 2: flash attention (no-max exp) + fused output projection.
// 256 WGs x 1024 thr (16 waves, 4/SIMD); wave w handles keys [w*256,+256)
// (K-split 16, 8 iterations).
// R7 diagnostic measured attn+gap ~= 14.75us; theory: F/Ht were written by
// proj WGs spread over all 8 XCDs, so ~7/8 of this kernel's reads miss the
// local L2 (cross-XCD, ~600-900cy via L3/fabric).  The old prefetch was
// 1-deep with a ~300cy body -> uncovered latency every iteration.
// THIS ROUND: 2-deep prefetch (consume fragments loaded 2 bodies ago).
// VGPR discipline: F-prefetch issued after QK (af_cur dead), V-prefetch
// after PV (bh_cur dead) -> peak ~120 VGPR, under the 128 cliff for
// 4 waves/SIMD; loop fully unrolled so rotation is register renaming.
// ---------------------------------------------------------------------------
__global__ __launch_bounds__(1024) void attn_kernel(
    const unsigned short* __restrict__ F, const unsigned short* __restrict__ G,
    const unsigned short* __restrict__ Ht,
    const void* __restrict__ x,
    const void* __restrict__ Wo, const void* __restrict__ bo,
    const void* __restrict__ gamma_p,
    void* __restrict__ out) {
    __shared__ __attribute__((aligned(16))) unsigned short P_sh[16][2][16][40];
    __shared__ float O_lds[16][32][32];
    __shared__ float l_lds[16][32];
    __shared__ float Om[32][33];
    __shared__ float lmg[32];
    __shared__ float WoL[32][64];
    __shared__ float boL[64];
    __shared__ int dflag;

    int tid = threadIdx.x;
    bool fp32 = detect_fp32(x, tid, &dflag);

    for (int i = tid; i < 2048; i += 1024) WoL[i >> 6][i & 63] = loadv(Wo, i, fp32);
    if (tid < 64) boL[tid] = loadv(bo, tid, fp32);

    int bx = blockIdx.x;            // 0..255
    int b = bx >> 7;                // batch
    int q0 = (bx & 127) << 5;       // 32 queries per WG
    int wave = tid >> 6;            // k-split index 0..15
    int lane = tid & 63;
    int Q = lane >> 4, l15 = lane & 15;

    const unsigned short* Fb = F + (b << 17);
    const unsigned short* Gb = G + (b << 17);
    const unsigned short* Htb = Ht + (b << 17);

    // B operands of S^T: queries as N.  g0 = q-tile [q0,q0+16), g1 = +16.
    short8 g0 = *(const short8*)(Gb + ((q0 + l15) << 5) + (Q << 3));
    short8 g1 = *(const short8*)(Gb + ((q0 + 16 + l15) << 5) + (Q << 3));

    f32x4 O00 = {0.f, 0.f, 0.f, 0.f}, O01 = O00, O10 = O00, O11 = O00;
    float ls0 = 0.f, ls1 = 0.f;

    int k_begin = wave << 8;        // 256 keys per wave

    // ---- 2-deep prefetch pipeline: cur = it, nxt = it+1 ----
    short8 af0_c = *(const short8*)(Fb + ((k_begin + l15) << 5) + (Q << 3));
    short8 af1_c = *(const short8*)(Fb + ((k_begin + 16 + l15) << 5) + (Q << 3));
    short8 bh0_c = *(const short8*)(Htb + (l15 << 12) + k_begin + (Q << 3));
    short8 bh1_c = *(const short8*)(Htb + ((16 + l15) << 12) + k_begin + (Q << 3));
    int k1 = k_begin + 32;
    short8 af0_n = *(const short8*)(Fb + ((k1 + l15) << 5) + (Q << 3));
    short8 af1_n = *(const short8*)(Fb + ((k1 + 16 + l15) << 5) + (Q << 3));
    short8 bh0_n = *(const short8*)(Htb + (l15 << 12) + k1 + (Q << 3));
    short8 bh1_n = *(const short8*)(Htb + ((16 + l15) << 12) + k1 + (Q << 3));

#pragma unroll
    for (int it = 0; it < 8; ++it) {
        int itn = (it < 6) ? it + 2 : 7;     // 2-ahead, clamped (redundant tail)
        int kn = k_begin + (itn << 5);

        // QK on current fragments (af*_c die here)
        f32x4 z = {0.f, 0.f, 0.f, 0.f};
        f32x4 c00 = __builtin_amdgcn_mfma_f32_16x16x32_bf16(af0_c, g0, z, 0, 0, 0);
        f32x4 c01 = __builtin_amdgcn_mfma_f32_16x16x32_bf16(af1_c, g0, z, 0, 0, 0);
        f32x4 c10 = __builtin_amdgcn_mfma_f32_16x16x32_bf16(af0_c, g1, z, 0, 0, 0);
        f32x4 c11 = __builtin_amdgcn_mfma_f32_16x16x32_bf16(af1_c, g1, z, 0, 0, 0);
        // c[r] = S[q][key = kk + half*16 + Q*4 + r], q = q-tile base + l15

        // issue F-prefetch for it+2 (af regs just freed)
        short8 tf0 = *(const short8*)(Fb + ((kn + l15) << 5) + (Q << 3));
        short8 tf1 = *(const short8*)(Fb + ((kn + 16 + l15) << 5) + (Q << 3));

        float e00[4], e01[4], e10[4], e11[4];
#pragma unroll
        for (int r = 0; r < 4; r++) {
            e00[r] = __expf(c00[r]); e01[r] = __expf(c01[r]);
            e10[r] = __expf(c10[r]); e11[r] = __expf(c11[r]);
            ls0 += e00[r] + e01[r];
            ls1 += e10[r] + e11[r];
        }

        // P (C-layout) -> LDS rows [query][key], bf16 by truncation
        uint2 w0, w1;
        w0.x = pack_trunc(e00[0], e00[1]); w0.y = pack_trunc(e00[2], e00[3]);
        w1.x = pack_trunc(e01[0], e01[1]); w1.y = pack_trunc(e01[2], e01[3]);
        *(uint2*)&P_sh[wave][0][l15][Q * 4] = w0;
        *(uint2*)&P_sh[wave][0][l15][16 + Q * 4] = w1;
        uint2 w2, w3;
        w2.x = pack_trunc(e10[0], e10[1]); w2.y = pack_trunc(e10[2], e10[3]);
        w3.x = pack_trunc(e11[0], e11[1]); w3.y = pack_trunc(e11[2], e11[3]);
        *(uint2*)&P_sh[wave][1][l15][Q * 4] = w2;
        *(uint2*)&P_sh[wave][1][l15][16 + Q * 4] = w3;

        // read back in A-layout: A[q=l15][k=Q*8+j]
        short8 pf0 = *(const short8*)&P_sh[wave][0][l15][Q * 8];
        short8 pf1 = *(const short8*)&P_sh[wave][1][l15][Q * 8];

        O00 = __builtin_amdgcn_mfma_f32_16x16x32_bf16(pf0, bh0_c, O00, 0, 0, 0);
        O01 = __builtin_amdgcn_mfma_f32_16x16x32_bf16(pf0, bh1_c, O01, 0, 0, 0);
        O10 = __builtin_amdgcn_mfma_f32_16x16x32_bf16(pf1, bh0_c, O10, 0, 0, 0);
        O11 = __builtin_amdgcn_mfma_f32_16x16x32_bf16(pf1, bh1_c, O11, 0, 0, 0);

        // issue V-prefetch for it+2 (bh regs just freed)
        short8 th0 = *(const short8*)(Htb + (l15 << 12) + kn + (Q << 3));
        short8 th1 = *(const short8*)(Htb + ((16 + l15) << 12) + kn + (Q << 3));

        // rotate pipeline (pure register renaming under full unroll)
        af0_c = af0_n; af1_c = af1_n; bh0_c = bh0_n; bh1_c = bh1_n;
        af0_n = tf0;   af1_n = tf1;   bh0_n = th0;   bh1_n = th1;
    }

    // per-wave l reduction across quads (each quad held distinct keys)
    ls0 += __shfl_xor(ls0, 16); ls0 += __shfl_xor(ls0, 32);
    ls1 += __shfl_xor(ls1, 16); ls1 += __shfl_xor(ls1, 32);
    if (Q == 0) {
        l_lds[wave][l15] = ls0;
        l_lds[wave][16 + l15] = ls1;
    }
    // O partials: D[row=q-in-tile=Q*4+r][col=cbar=l15]
#pragma unroll
    for (int r = 0; r < 4; r++) {
        O_lds[wave][(Q << 2) | r][l15]             = O00[r];
        O_lds[wave][(Q << 2) | r][16 + l15]        = O01[r];
        O_lds[wave][16 + ((Q << 2) | r)][l15]      = O10[r];
        O_lds[wave][16 + ((Q << 2) | r)][16 + l15] = O11[r];
    }
    __syncthreads();

    // merge k-split partials (plain sums)
    if (tid < 32) {
        float s = 0.f;
#pragma unroll
        for (int w = 0; w < 16; w++) s += l_lds[w][tid];
        lmg[tid] = 1.0f / s;
    }
    {
        int q = tid >> 5, c = tid & 31;   // 1024 threads = 1024 elements
        float s = 0.f;
#pragma unroll
        for (int w = 0; w < 16; w++) s += O_lds[w][q][c];
        Om[q][c] = s;
    }
    __syncthreads();

    // output projection + residual: thread -> (q = tid>>5, 2 channels)
    int q = tid >> 5;
    int ch = (tid & 31) << 1;
    float a0 = 0.f, a1 = 0.f;
#pragma unroll
    for (int c = 0; c < 32; c++) {
        float ob = Om[q][c];
        f32x2 wr = *(const f32x2*)&WoL[c][ch];
        a0 += ob * wr[0]; a1 += ob * wr[1];
    }
    float inv = lmg[q];
    float gam = loadv(gamma_p, 0, fp32);
    int gq = q0 + q;
    int obase = (((b << 12) + gq) << 6) + ch;
    if (fp32) {
        f32x2 xv = *(const f32x2*)((const float*)x + obase);
        f32x2 ov;
        ov[0] = xv[0] + gam * (a0 * inv + boL[ch + 0]);
        ov[1] = xv[1] + gam * (a1 * inv + boL[ch + 1]);
        *(f32x2*)((float*)out + obase) = ov;
    } else {
        const unsigned short* xb = (const unsigned short*)x;
        unsigned short* ob16 = (unsigned short*)out;
        unsigned int pk = pack2(bf2f(xb[obase + 0]) + gam * (a0 * inv + boL[ch + 0]),
                                bf2f(xb[obase + 1]) + gam * (a1 * inv + boL[ch + 1]));
        *(unsigned int*)(ob16 + obase) = pk;
    }
}

extern "C" void kernel_launch(void* const* d_in, const int* in_sizes, int n_in,
                              void* d_out, int out_size, void* d_ws, size_t ws_size,
                              hipStream_t stream) {
    const void* x   = d_in[0];
    const void* Wf  = d_in[1];
    const void* bfv = d_in[2];
    const void* Wg  = d_in[3];
    const void* bgv = d_in[4];
    const void* Wh  = d_in[5];
    const void* bhv = d_in[6];
    const void* Wo  = d_in[7];
    const void* bo  = d_in[8];
    const void* gam = d_in[9];

    unsigned short* F  = (unsigned short*)d_ws;       // [B][N][32] bf16
    unsigned short* G  = F + 262144;                  // [B][N][32] bf16
    unsigned short* Ht = G + 262144;                  // [B][32][N] bf16

    proj_kernel<<<256, 512, 0, stream>>>(x, Wf, bfv, Wg, bgv, Wh, bhv, F, G, Ht);
    attn_kernel<<<256, 1024, 0, stream>>>(F, G, Ht, x, Wo, bo, gam, d_out);
}